// Round 3
// baseline (1543.761 us; speedup 1.0000x reference)
//
#include <hip/hip_runtime.h>
#include <cstddef>

#define NXS 64
#define NUS 32
#define NYS 32
#define NWS 64
#define BBATCH 256
#define TT  2048

// ws float layout:
//  [0,     12288)  Wzt (192x64): rows 0..63 x-part, 64..95 u-part, 96..159 w-part, 160..191 u_t-part
//  [12288, 24576)  Wxt (192x64): same row semantics (160..191 zero)
//  [24576, 30720)  Wyt (192x32): same row semantics (160..191 zero)
#define WS_WZT  0
#define WS_WXT  12288
#define WS_WYT  24576

typedef float v2f __attribute__((ext_vector_type(2)));

__device__ __forceinline__ float fast_tanh(float x) {
    float e = __expf(2.0f * x);
    return 1.0f - 2.0f * __builtin_amdgcn_rcpf(e + 1.0f);
}

template<int CTRL>
__device__ __forceinline__ float dpp_row_add(float v) {
    int t = __builtin_amdgcn_update_dpp(0, __float_as_int(v), CTRL, 0xF, 0xF, true);
    return v + __int_as_float(t);
}

// barrier that drains only LDS (lgkm), leaving global loads/stores in flight
__device__ __forceinline__ void step_barrier() {
    asm volatile("s_waitcnt lgkmcnt(0)\n\ts_barrier" ::: "memory");
}

// ---------------------------------------------------------------------------
__global__ __launch_bounds__(1024) void setup_kernel(const float* __restrict__ Y,
                                                     const float* __restrict__ lam,
                                                     const float* __restrict__ A,
                                                     const float* __restrict__ B1,
                                                     const float* __restrict__ B2,
                                                     const float* __restrict__ C1,
                                                     const float* __restrict__ D11,
                                                     const float* __restrict__ D12,
                                                     const float* __restrict__ C2,
                                                     const float* __restrict__ D21,
                                                     float* __restrict__ ws) {
    __shared__ float M[64 * 129];
    __shared__ float rowk[128];
    __shared__ float ck[64];
    __shared__ float WxL[96 * 64];
    __shared__ float WxwL[64 * 64];
    const int tid = threadIdx.x;

    for (int idx = tid; idx < 64 * 64; idx += 1024) {
        int r = idx >> 6, c = idx & 63;
        M[r * 129 + c]      = Y[idx];
        M[r * 129 + 64 + c] = (r == c) ? 1.0f : 0.0f;
    }
    __syncthreads();

    for (int k = 0; k < 64; ++k) {
        float dv = 1.0f / M[k * 129 + k];
        if (tid < 128) rowk[tid] = M[k * 129 + tid] * dv;
        if (tid >= 128 && tid < 192) ck[tid - 128] = M[(tid - 128) * 129 + k];
        __syncthreads();
        for (int idx = tid; idx < 64 * 128; idx += 1024) {
            int r = idx >> 7, c = idx & 127;
            float cur = M[r * 129 + c];
            M[r * 129 + c] = (r == k) ? rowk[c] : cur - ck[r] * rowk[c];
        }
        __syncthreads();
    }
    // Yinv[m][j] = M[m*129 + 64 + j]

    // phase 2
    for (int idx = tid; idx < 6144; idx += 1024) {       // Wx rows 0..95 of Wxt
        int k = idx >> 6, j = idx & 63;
        float s = 0.0f;
        if (k < 64) {
            #pragma unroll 8
            for (int m = 0; m < 64; ++m) s += A[m * 64 + k] * M[m * 129 + 64 + j];
        } else {
            int ku = k - 64;
            #pragma unroll 8
            for (int m = 0; m < 64; ++m) s += B1[m * 32 + ku] * M[m * 129 + 64 + j];
        }
        WxL[idx] = s;
        ws[WS_WXT + idx] = s;
    }
    for (int idx = tid; idx < 4096; idx += 1024) {       // Wxw rows 96..159 of Wxt
        int k = idx >> 6, j = idx & 63;
        float s = 0.0f;
        #pragma unroll 8
        for (int m = 0; m < 64; ++m) s += B2[m * 64 + k] * M[m * 129 + 64 + j];
        WxwL[idx] = s;
        ws[WS_WXT + 6144 + idx] = s;
    }
    for (int idx = tid; idx < 2048; idx += 1024)         // Wxt rows 160..191 = 0
        ws[WS_WXT + 10240 + idx] = 0.0f;
    for (int idx = tid; idx < 2048; idx += 1024) {       // Wzu rows 160..191 of Wzt
        int k = idx >> 6, j = idx & 63;
        ws[WS_WZT + 10240 + idx] = D21[j * 32 + k] / lam[j];
    }
    for (int idx = tid; idx < 5120; idx += 1024) {       // Wyt rows 0..159
        int k = idx >> 5, j = idx & 31;
        float v = (k < 64) ? C1[j * 64 + k]
                : (k < 96) ? D11[j * 32 + (k - 64)]
                           : D12[j * 64 + (k - 96)];
        ws[WS_WYT + idx] = v;
    }
    for (int idx = tid; idx < 1024; idx += 1024)         // Wyt rows 160..191 = 0
        ws[WS_WYT + 5120 + idx] = 0.0f;
    __syncthreads();

    // phase 3: Wzz, Wwz
    for (int idx = tid; idx < 6144; idx += 1024) {
        int k = idx >> 6, j = idx & 63;
        float s = 0.0f;
        #pragma unroll 8
        for (int m = 0; m < 64; ++m) s += WxL[k * 64 + m] * C2[j * 64 + m];
        ws[WS_WZT + idx] = s / lam[j];
    }
    for (int idx = tid; idx < 4096; idx += 1024) {
        int k = idx >> 6, j = idx & 63;
        float s = 0.0f;
        #pragma unroll 8
        for (int m = 0; m < 64; ++m) s += WxwL[k * 64 + m] * C2[j * 64 + m];
        ws[WS_WZT + 6144 + idx] = s / lam[j];
    }
}

// ---------------------------------------------------------------------------
// Scan v3: TWO independent batch chains per block (grid = 128). Same 8-wave
// role split as v2; weights shared in registers, state/ring/u duplicated per
// chain in LDS. Each wave interleaves chain-0 and chain-1 work per step so
// one chain's LDS/DPP/tanh latency hides under the other's issue stream.
__global__ __launch_bounds__(512, 2) void rnn3_kernel(const float* __restrict__ xp,
                                                      const float* __restrict__ ws,
                                                      float* __restrict__ out) {
    const int b0   = blockIdx.x * 2;
    const int tid  = threadIdx.x;
    const int wv   = tid >> 6;
    const int lane = tid & 63;
    const int p    = lane & 15;
    const int o    = lane >> 4;
    const int sw   = (p >> 2) & 1;

    __shared__ __align__(16) float sbuf[2][2][128];        // [chain][pp][...]
    __shared__ __align__(16) float sring[2][2][16][160];   // [chain][buf][slot][...]
    __shared__ __align__(16) float uR[2][32][32];          // [chain][step&31][...]

    const float* __restrict__ Wzt = ws + WS_WZT;
    const float* __restrict__ Wxt = ws + WS_WXT;
    const float* __restrict__ Wyt = ws + WS_WYT;

    const float4* __restrict__ xp4A = (const float4*)(xp + (size_t)b0 * (TT * NUS));
    const float4* __restrict__ xp4B = (const float4*)(xp + (size_t)(b0 + 1) * (TT * NUS));
    const size_t ybA  = (size_t)b0 * (TT * NYS);
    const size_t ybB  = (size_t)(b0 + 1) * (TT * NYS);
    const size_t xoff = (size_t)BBATCH * TT * NYS;

    // init: uR rows 0..15 = u_0..15, row 31 = u_{-1}=0; sbuf[ch][1] = S'_{-1}=0
    {
        const float4 z4 = make_float4(0.f, 0.f, 0.f, 0.f);
        if (tid < 128) {
            int s = tid >> 3, q = tid & 7;
            *(float4*)&uR[0][s][q * 4] = xp4A[s * 8 + q];
        } else if (tid < 256) {
            int t = tid - 128, s = t >> 3, q = t & 7;
            *(float4*)&uR[1][s][q * 4] = xp4B[s * 8 + q];
        } else if (tid < 264) {
            *(float4*)&uR[0][31][(tid - 256) * 4] = z4;
        } else if (tid < 272) {
            *(float4*)&uR[1][31][(tid - 264) * 4] = z4;
        } else if (tid < 304) {
            ((float4*)&sbuf[0][1][0])[tid - 272] = z4;
        } else if (tid < 336) {
            ((float4*)&sbuf[1][1][0])[tid - 304] = z4;
        }
    }
    __syncthreads();

    const bool q1 = (p & 3) == 1, q2 = (p & 3) == 2, q3 = (p & 3) == 3;

    if (wv < 4) {
        // ===================== Z waves: z -> tanh -> w; ring gz ============
        const int g   = wv;
        const int rz  = 4 * g + o;
        const int jzb = 4 * rz;
        const int zo  = jzb + (p & 3);
        v2f wz2[4][4];
        #pragma unroll
        for (int k2 = 0; k2 < 4; ++k2) {
            int row = 8 * p + 2 * ((k2 + 2 * sw) & 3);
            int r0  = row + (row >= 64 ? 32 : 0);          // remap to old layout
            #pragma unroll
            for (int r = 0; r < 4; ++r)
                wz2[k2][r] = (v2f){ Wzt[r0 * 64 + jzb + r], Wzt[(r0 + 1) * 64 + jzb + r] };
        }
        v2f zu1[16], zu2[16];
        #pragma unroll
        for (int mm = 0; mm < 16; ++mm) {
            zu1[mm] = (v2f){ Wzt[(64  + 2 * mm) * 64 + lane], Wzt[(65  + 2 * mm) * 64 + lane] };
            zu2[mm] = (v2f){ Wzt[(160 + 2 * mm) * 64 + lane], Wzt[(161 + 2 * mm) * 64 + lane] };
        }

        auto ringZ = [&](int ch, int e) {
            const float4* P = (const float4*)uR[ch][(e - 1) & 31];
            const float4* C = (const float4*)uR[ch][e & 31];
            v2f a = (v2f){0.f, 0.f};
            #pragma unroll
            for (int q = 0; q < 8; ++q) {
                float4 up = P[q];
                float4 uc = C[q];
                a += (v2f){up.x, up.y} * zu1[2 * q] + (v2f){up.z, up.w} * zu1[2 * q + 1];
                a += (v2f){uc.x, uc.y} * zu2[2 * q] + (v2f){uc.z, uc.w} * zu2[2 * q + 1];
            }
            sring[ch][(e >> 4) & 1][e & 15][lane] = a.x + a.y;
        };

        #pragma unroll
        for (int j = 0; j < 4; ++j) { ringZ(0, 4 * g + j); ringZ(1, 4 * g + j); }
        __syncthreads();

        auto stepZ = [&](int ch, int rp, int wp, float gst) {
            const float4* sb4 = (const float4*)&sbuf[ch][rp][0];
            float4 Ra = sb4[2 * p + sw];
            float4 Rb = sb4[2 * p + 1 - sw];
            v2f av[4] = { {Ra.x, Ra.y}, {Ra.z, Ra.w}, {Rb.x, Rb.y}, {Rb.z, Rb.w} };
            v2f c0 = {0.f, 0.f}, c1 = c0, c2 = c0, c3 = c0;
            #pragma unroll
            for (int k2 = 0; k2 < 4; ++k2) {
                c0 += av[k2] * wz2[k2][0]; c1 += av[k2] * wz2[k2][1];
                c2 += av[k2] * wz2[k2][2]; c3 += av[k2] * wz2[k2][3];
            }
            float h0 = c0.x + c0.y, h1 = c1.x + c1.y, h2 = c2.x + c2.y, h3 = c3.x + c3.y;
            h0 = dpp_row_add<0xB1>(h0); h0 = dpp_row_add<0x4E>(h0);
            h1 = dpp_row_add<0xB1>(h1); h1 = dpp_row_add<0x4E>(h1);
            h2 = dpp_row_add<0xB1>(h2); h2 = dpp_row_add<0x4E>(h2);
            h3 = dpp_row_add<0xB1>(h3); h3 = dpp_row_add<0x4E>(h3);
            float dz = h0;
            dz = q1 ? h1 : dz; dz = q2 ? h2 : dz; dz = q3 ? h3 : dz;
            dz = dpp_row_add<0x124>(dz); dz = dpp_row_add<0x128>(dz);
            float wvv = fast_tanh(dz + gst);
            if (p < 4) sbuf[ch][wp][64 + zo] = wvv;
        };

        const int chf = g >> 1;                            // fetch chain for this wave
        const float4* __restrict__ xpf = (chf == 0) ? xp4A : xp4B;
        const int t7 = tid & 127;
        float4 ufetch;

        for (int c = 0; c < TT / 16; ++c) {
            #pragma unroll
            for (int off = 0; off < 16; ++off) {
                const int rp = (off + 1) & 1, wp = off & 1;
                if (off == 0 && c + 1 < TT / 16) {
                    int s = 16 * (c + 1) + (t7 >> 3);
                    ufetch = xpf[s * 8 + (t7 & 7)];
                }
                if (off == 4 && c + 1 < TT / 16) {
                    int s = 16 * (c + 1) + (t7 >> 3);
                    *(float4*)&uR[chf][s & 31][(t7 & 7) * 4] = ufetch;
                }
                if (off == 5 || off == 8 || off == 11 || off == 14)
                    ringZ(0, 16 * (c + 1) + 4 * g + (off - 5) / 3);
                if (off == 6 || off == 9 || off == 12 || off == 15)
                    ringZ(1, 16 * (c + 1) + 4 * g + (off - 6) / 3);

                float gstA = sring[0][c & 1][off][zo];
                float gstB = sring[1][c & 1][off][zo];
                stepZ(0, rp, wp, gstA);
                stepZ(1, rp, wp, gstB);
                step_barrier();
            }
        }
    } else {
        // ===================== X waves: x', y; ring gx/gy ==================
        const int g    = wv - 4;
        const int rx   = 4 * g + o;
        const int jxb  = 4 * rx;
        const int jyb  = 2 * rx;
        const int xo   = (p < 4) ? (64 + jxb + (p & 3)) : (128 + jyb + (p & 1));
        const int ycol = jyb + (p & 1);
        const bool qy  = (p & 1) != 0;
        v2f wx2[4][4], wy2[4][2];
        #pragma unroll
        for (int k2 = 0; k2 < 4; ++k2) {
            int row = 8 * p + 2 * ((k2 + 2 * sw) & 3);
            int r0  = row + (row >= 64 ? 32 : 0);
            #pragma unroll
            for (int r = 0; r < 4; ++r)
                wx2[k2][r] = (v2f){ Wxt[r0 * 64 + jxb + r], Wxt[(r0 + 1) * 64 + jxb + r] };
            wy2[k2][0] = (v2f){ Wyt[r0 * 32 + jyb],     Wyt[(r0 + 1) * 32 + jyb] };
            wy2[k2][1] = (v2f){ Wyt[r0 * 32 + jyb + 1], Wyt[(r0 + 1) * 32 + jyb + 1] };
        }
        const int l31 = lane & 31;
        v2f xu[16], yu[16];
        #pragma unroll
        for (int mm = 0; mm < 16; ++mm) {
            xu[mm] = (v2f){ Wxt[(64 + 2 * mm) * 64 + lane], Wxt[(65 + 2 * mm) * 64 + lane] };
            yu[mm] = (v2f){ Wyt[(64 + 2 * mm) * 32 + l31],  Wyt[(65 + 2 * mm) * 32 + l31] };
        }

        auto ringX = [&](int ch, int e) {
            const float4* P = (const float4*)uR[ch][(e - 1) & 31];
            v2f ax = (v2f){0.f, 0.f}, ay = ax;
            #pragma unroll
            for (int q = 0; q < 8; ++q) {
                float4 up = P[q];
                v2f u0 = {up.x, up.y}, u1 = {up.z, up.w};
                ax += u0 * xu[2 * q] + u1 * xu[2 * q + 1];
                ay += u0 * yu[2 * q] + u1 * yu[2 * q + 1];
            }
            const int nb = (e >> 4) & 1, sl = e & 15;
            sring[ch][nb][sl][64 + lane] = ax.x + ax.y;
            if (lane < 32) sring[ch][nb][sl][128 + lane] = ay.x + ay.y;
        };

        #pragma unroll
        for (int j = 0; j < 4; ++j) { ringX(0, 4 * g + j); ringX(1, 4 * g + j); }
        __syncthreads();

        float ybatA[16], ybatB[16];

        auto computeX = [&](const float* Sb, float& dxo, float& dyo) {
            const float4* sb4 = (const float4*)Sb;
            float4 Ra = sb4[2 * p + sw];
            float4 Rb = sb4[2 * p + 1 - sw];
            v2f av[4] = { {Ra.x, Ra.y}, {Ra.z, Ra.w}, {Rb.x, Rb.y}, {Rb.z, Rb.w} };
            v2f c0 = {0.f, 0.f}, c1 = c0, c2 = c0, c3 = c0, d0 = c0, d1 = c0;
            #pragma unroll
            for (int k2 = 0; k2 < 4; ++k2) {
                c0 += av[k2] * wx2[k2][0]; c1 += av[k2] * wx2[k2][1];
                c2 += av[k2] * wx2[k2][2]; c3 += av[k2] * wx2[k2][3];
                d0 += av[k2] * wy2[k2][0]; d1 += av[k2] * wy2[k2][1];
            }
            float h0 = c0.x + c0.y, h1 = c1.x + c1.y, h2 = c2.x + c2.y, h3 = c3.x + c3.y;
            float e0 = d0.x + d0.y, e1 = d1.x + d1.y;
            h0 = dpp_row_add<0xB1>(h0); h0 = dpp_row_add<0x4E>(h0);
            h1 = dpp_row_add<0xB1>(h1); h1 = dpp_row_add<0x4E>(h1);
            h2 = dpp_row_add<0xB1>(h2); h2 = dpp_row_add<0x4E>(h2);
            h3 = dpp_row_add<0xB1>(h3); h3 = dpp_row_add<0x4E>(h3);
            e0 = dpp_row_add<0xB1>(e0); e0 = dpp_row_add<0x4E>(e0);
            e1 = dpp_row_add<0xB1>(e1); e1 = dpp_row_add<0x4E>(e1);
            float dx = h0;
            dx = q1 ? h1 : dx; dx = q2 ? h2 : dx; dx = q3 ? h3 : dx;
            dx = dpp_row_add<0x124>(dx); dx = dpp_row_add<0x128>(dx);
            float dy = qy ? e1 : e0;
            dy = dpp_row_add<0x124>(dy); dy = dpp_row_add<0x128>(dy);
            dxo = dx; dyo = dy;
        };

        for (int c = 0; c < TT / 16; ++c) {
            #pragma unroll
            for (int off = 0; off < 16; ++off) {
                const int rp = (off + 1) & 1, wp = off & 1;
                if (off == 5 || off == 8 || off == 11 || off == 14)
                    ringX(0, 16 * (c + 1) + 4 * g + (off - 5) / 3);
                if (off == 6 || off == 9 || off == 12 || off == 15)
                    ringX(1, 16 * (c + 1) + 4 * g + (off - 6) / 3);

                float gstA = sring[0][c & 1][off][xo];
                float gstB = sring[1][c & 1][off][xo];
                float dxA, dyA, dxB, dyB;
                computeX(&sbuf[0][rp][0], dxA, dyA);
                computeX(&sbuf[1][rp][0], dxB, dyB);
                if (p < 4) {
                    sbuf[0][wp][jxb + (p & 3)] = dxA + gstA;
                    sbuf[1][wp][jxb + (p & 3)] = dxB + gstB;
                }
                ybatA[(off + 15) & 15] = dyA + gstA;       // y_{i-1}
                ybatB[(off + 15) & 15] = dyB + gstB;
                if (off == 0 && c >= 1 && (p == 4 || p == 5)) {
                    size_t baseA = ybA + (size_t)(16 * c - 16) * NYS + ycol;
                    size_t baseB = ybB + (size_t)(16 * c - 16) * NYS + ycol;
                    #pragma unroll
                    for (int s = 0; s < 16; ++s) {
                        out[baseA + (size_t)s * NYS] = ybatA[s];
                        out[baseB + (size_t)s * NYS] = ybatB[s];
                    }
                }
                step_barrier();
            }
        }

        // epilogue: y_2047 + x_final from S'_2047 (pp=1); ring entry 2048 at [0][0]
        {
            float gstA = sring[0][0][0][xo];
            float gstB = sring[1][0][0][xo];
            float dxA, dyA, dxB, dyB;
            computeX(&sbuf[0][1][0], dxA, dyA);
            computeX(&sbuf[1][1][0], dxB, dyB);
            if (p < 4) {
                out[xoff + (size_t)b0 * 64 + jxb + (p & 3)]       = dxA + gstA;
                out[xoff + (size_t)(b0 + 1) * 64 + jxb + (p & 3)] = dxB + gstB;
            }
            ybatA[15] = dyA + gstA;
            ybatB[15] = dyB + gstB;
            if (p == 4 || p == 5) {
                size_t baseA = ybA + (size_t)(TT - 16) * NYS + ycol;
                size_t baseB = ybB + (size_t)(TT - 16) * NYS + ycol;
                #pragma unroll
                for (int s = 0; s < 16; ++s) {
                    out[baseA + (size_t)s * NYS] = ybatA[s];
                    out[baseB + (size_t)s * NYS] = ybatB[s];
                }
            }
        }
    }
}

// ---------------------------------------------------------------------------
extern "C" void kernel_launch(void* const* d_in, const int* in_sizes, int n_in,
                              void* d_out, int out_size, void* d_ws, size_t ws_size,
                              hipStream_t stream) {
    const float* xp  = (const float*)d_in[0];
    const float* Y   = (const float*)d_in[1];
    const float* lam = (const float*)d_in[2];
    const float* A   = (const float*)d_in[3];
    const float* B1  = (const float*)d_in[4];
    const float* B2  = (const float*)d_in[5];
    const float* C1  = (const float*)d_in[6];
    const float* D11 = (const float*)d_in[7];
    const float* D12 = (const float*)d_in[8];
    const float* C2  = (const float*)d_in[9];
    const float* D21 = (const float*)d_in[10];
    float* out = (float*)d_out;
    float* ws  = (float*)d_ws;

    hipLaunchKernelGGL(setup_kernel, dim3(1), dim3(1024), 0, stream,
                       Y, lam, A, B1, B2, C1, D11, D12, C2, D21, ws);
    hipLaunchKernelGGL(rnn3_kernel, dim3(BBATCH / 2), dim3(512), 0, stream, xp, ws, out);
}

// Round 4
// 1106.913 us; speedup vs baseline: 1.3947x; 1.3947x over previous
//
#include <hip/hip_runtime.h>
#include <cstddef>

#define NXS 64
#define NUS 32
#define NYS 32
#define NWS 64
#define BBATCH 256
#define TT  2048

// ws float layout (final, after all setup kernels):
//  [0,     12288)  Wzt (192x64): rows 0..63 x-part, 64..95 u-part, 96..159 w-part, 160..191 u_t-part
//  [12288, 24576)  Wxt (192x64): same row semantics (160..191 zero)
//  [24576, 30720)  Wyt (192x32): same row semantics (160..191 zero)
// Staging: setup_inv writes Yinv (64x64) into ws[WS_WZT..+4096); setup_fold
// reads it (writes Wxt/Wyt/Wzu); setup_wz overwrites Wzt rows 0..159 last.
#define WS_WZT  0
#define WS_WXT  12288
#define WS_WYT  24576

// scan LDS geometry: S' = [x(64) | pad(8) | w(64)] -> conflict-free dual streams
#define SB   136
#define WOFF 72

typedef float v2f __attribute__((ext_vector_type(2)));

__device__ __forceinline__ float fast_tanh(float x) {
    float e = __expf(2.0f * x);
    return 1.0f - 2.0f * __builtin_amdgcn_rcpf(e + 1.0f);
}

template<int CTRL>
__device__ __forceinline__ float dpp_row_add(float v) {
    int t = __builtin_amdgcn_update_dpp(0, __float_as_int(v), CTRL, 0xF, 0xF, true);
    return v + __int_as_float(t);
}

// barrier that drains only LDS (lgkm), leaving global loads/stores in flight
__device__ __forceinline__ void step_barrier() {
    asm volatile("s_waitcnt lgkmcnt(0)\n\ts_barrier" ::: "memory");
}

// ---------------------------------------------------------------------------
// setup 1/3: Yinv via Gauss-Jordan (1 block). Writes Yinv to ws[WS_WZT..+4096).
__global__ __launch_bounds__(1024) void setup_inv_kernel(const float* __restrict__ Y,
                                                         float* __restrict__ ws) {
    __shared__ float M[64 * 129];
    __shared__ float rowk[128];
    __shared__ float ck[64];
    const int tid = threadIdx.x;

    for (int idx = tid; idx < 64 * 64; idx += 1024) {
        int r = idx >> 6, c = idx & 63;
        M[r * 129 + c]      = Y[idx];
        M[r * 129 + 64 + c] = (r == c) ? 1.0f : 0.0f;
    }
    __syncthreads();

    for (int k = 0; k < 64; ++k) {
        float dv = 1.0f / M[k * 129 + k];
        if (tid < 128) rowk[tid] = M[k * 129 + tid] * dv;
        if (tid >= 128 && tid < 192) ck[tid - 128] = M[(tid - 128) * 129 + k];
        __syncthreads();
        for (int idx = tid; idx < 64 * 128; idx += 1024) {
            int r = idx >> 7, c = idx & 127;
            float cur = M[r * 129 + c];
            M[r * 129 + c] = (r == k) ? rowk[c] : cur - ck[r] * rowk[c];
        }
        __syncthreads();
    }
    for (int idx = tid; idx < 4096; idx += 1024) {
        int r = idx >> 6, c = idx & 63;
        ws[WS_WZT + idx] = M[r * 129 + 64 + c];
    }
}

// ---------------------------------------------------------------------------
// setup 2/3: fold Yinv into Wxt; copy Wyt; build Wzu. 16 blocks x 256.
__global__ __launch_bounds__(256) void setup_fold_kernel(const float* __restrict__ lam,
                                                         const float* __restrict__ A,
                                                         const float* __restrict__ B1,
                                                         const float* __restrict__ B2,
                                                         const float* __restrict__ C1,
                                                         const float* __restrict__ D11,
                                                         const float* __restrict__ D12,
                                                         const float* __restrict__ D21,
                                                         float* ws) {
    const float* Yinv = ws + WS_WZT;   // staged by setup_inv_kernel
    for (int idx = blockIdx.x * 256 + threadIdx.x; idx < 20480; idx += 16 * 256) {
        if (idx < 12288) {                       // Wxt element (k, j)
            int k = idx >> 6, j = idx & 63;
            float s = 0.0f;
            if (k < 64) {
                #pragma unroll 8
                for (int m = 0; m < 64; ++m) s += A[m * 64 + k] * Yinv[m * 64 + j];
            } else if (k < 96) {
                int ku = k - 64;
                #pragma unroll 8
                for (int m = 0; m < 64; ++m) s += B1[m * 32 + ku] * Yinv[m * 64 + j];
            } else if (k < 160) {
                int kw = k - 96;
                #pragma unroll 8
                for (int m = 0; m < 64; ++m) s += B2[m * 64 + kw] * Yinv[m * 64 + j];
            }
            ws[WS_WXT + idx] = s;
        } else if (idx < 18432) {                // Wyt element
            int t = idx - 12288;
            int k = t >> 5, j = t & 31;
            float v = (k < 64)  ? C1[j * 64 + k]
                    : (k < 96)  ? D11[j * 32 + (k - 64)]
                    : (k < 160) ? D12[j * 64 + (k - 96)]
                                : 0.0f;
            ws[WS_WYT + t] = v;
        } else {                                 // Wzu rows 160..191 of Wzt
            int t = idx - 18432;
            int k = t >> 6, j = t & 63;
            ws[WS_WZT + 10240 + t] = D21[j * 32 + k] / lam[j];
        }
    }
}

// ---------------------------------------------------------------------------
// setup 3/3: Wzz/Wwz = (Wxt rows 0..159) @ C2^T * Tinv. 16 blocks x 256.
// Overwrites Wzt rows 0..159 (incl. the Yinv staging area) - runs last.
__global__ __launch_bounds__(256) void setup_wz_kernel(const float* __restrict__ lam,
                                                       const float* __restrict__ C2,
                                                       float* ws) {
    for (int idx = blockIdx.x * 256 + threadIdx.x; idx < 10240; idx += 16 * 256) {
        int k = idx >> 6, j = idx & 63;
        float s = 0.0f;
        #pragma unroll 8
        for (int m = 0; m < 64; ++m) s += ws[WS_WXT + k * 64 + m] * C2[j * 64 + m];
        ws[WS_WZT + idx] = s / lam[j];
    }
}

// ---------------------------------------------------------------------------
// Scan v4: output-pair layout, no transpose-reduce.
//   threads 0..127  : W-group  (w outputs 0..63;  j = q>>1, K-half h = q&1)
//   threads 128..255: X-group  (x outputs)
//   threads 256..319: Y-group  (y outputs 0..31)
//   wave 5 (320..383): ring gz ; wave 6 (384..447): ring gx
//   wave 7 (448..511): ring gy (lanes<32) + u prefetch
// Consumer lane dots its 64-dim half of S'=[x|pad|w] (broadcast b128 reads,
// x at word 0, w at word 72 -> disjoint banks), combines halves with ONE
// quad_perm DPP add. Ring entry e = [gz(64)|gx(64)|gy(32)], produced 16 steps
// ahead into the opposite sring buffer; consumed as +gst.
__global__ __launch_bounds__(512, 2) void rnn4_kernel(const float* __restrict__ xp,
                                                      const float* __restrict__ ws,
                                                      float* __restrict__ out) {
    const int b   = blockIdx.x;
    const int tid = threadIdx.x;

    __shared__ __align__(16) float sbuf[2][SB];
    __shared__ __align__(16) float sring[2][16][160];
    __shared__ __align__(16) float uR[32][32];     // u step s -> uR[s&31]

    const float* __restrict__ Wzt = ws + WS_WZT;
    const float* __restrict__ Wxt = ws + WS_WXT;
    const float* __restrict__ Wyt = ws + WS_WYT;

    const float4* __restrict__ xp4 = (const float4*)(xp + (size_t)b * (TT * NUS));
    const size_t yb   = (size_t)b * (TT * NYS);
    const size_t xoff = (size_t)BBATCH * TT * NYS;

    // ---- init: uR slots 0..31 = u_0..31 ; sbuf[1] = S'_{-1} = 0 ----
    if (tid < 256) {
        int s = tid >> 3, q = tid & 7;
        *(float4*)&uR[s][q * 4] = xp4[s * 8 + q];
    } else if (tid < 290) {
        ((float4*)&sbuf[1][0])[tid - 256] = make_float4(0.f, 0.f, 0.f, 0.f);
    }
    __syncthreads();

    if (tid < 320) {
        // =================== consumer lanes (W / X / Y) ===================
        const int role = (tid < 128) ? 0 : (tid < 256) ? 1 : 2;
        const int q    = tid - ((role == 0) ? 0 : (role == 1) ? 128 : 256);
        const int j    = q >> 1;
        const int h    = q & 1;
        const int LD   = (role == 2) ? 32 : 64;
        const int scol = (role == 0) ? 0 : (role == 1) ? 64 : 128;
        const float* Wt = (role == 0) ? Wzt : (role == 1) ? Wxt : Wyt;
        const int rbase = h ? 96 : 0;

        v2f wv[32];
        #pragma unroll
        for (int t = 0; t < 32; ++t)
            wv[t] = (v2f){ Wt[(rbase + 2 * t) * LD + j], Wt[(rbase + 2 * t + 1) * LD + j] };

        float ybat[16];
        const size_t xfo = xoff + (size_t)b * 64 + j;

        // one barrier to match ring-prologue phase
        __syncthreads();

        auto dot = [&](const float* Sb) -> float {
            const float4* sb4 = (const float4*)(Sb + (h ? WOFF : 0));
            v2f a0 = {0.f, 0.f}, a1 = a0, a2 = a0, a3 = a0;
            #pragma unroll
            for (int m = 0; m < 16; m += 4) {
                float4 s0 = sb4[m], s1 = sb4[m + 1], s2 = sb4[m + 2], s3 = sb4[m + 3];
                a0 += (v2f){s0.x, s0.y} * wv[2 * m]     + (v2f){s0.z, s0.w} * wv[2 * m + 1];
                a1 += (v2f){s1.x, s1.y} * wv[2 * m + 2] + (v2f){s1.z, s1.w} * wv[2 * m + 3];
                a2 += (v2f){s2.x, s2.y} * wv[2 * m + 4] + (v2f){s2.z, s2.w} * wv[2 * m + 5];
                a3 += (v2f){s3.x, s3.y} * wv[2 * m + 6] + (v2f){s3.z, s3.w} * wv[2 * m + 7];
            }
            v2f a = (a0 + a1) + (a2 + a3);
            float part = a.x + a.y;
            return dpp_row_add<0xB1>(part);   // pair lanes (2j,2j+1) -> full sum
        };

        #pragma unroll 2
        for (int i = 0; i < TT; ++i) {
            const int rp = (i + 1) & 1, wp = i & 1;
            float tot = dot(&sbuf[rp][0]);
            float gst = sring[(i >> 4) & 1][i & 15][scol + j];
            if (role == 0) {
                float wvv = fast_tanh(tot + gst);
                if (!h) sbuf[wp][WOFF + j] = wvv;
            } else if (role == 1) {
                if (!h) sbuf[wp][j] = tot + gst;
            } else {
                ybat[(i + 15) & 15] = tot + gst;           // y_{i-1}
                if ((i & 15) == 0 && i >= 16 && !h) {
                    size_t base = yb + (size_t)(i - 16) * NYS + j;
                    #pragma unroll
                    for (int s = 0; s < 16; ++s) out[base + (size_t)s * NYS] = ybat[s];
                }
            }
            step_barrier();
        }

        // ---- epilogue: x_final and y_{TT-1} from S'_{TT-1} (sbuf[1]) ----
        if (role == 1) {
            float tot = dot(&sbuf[1][0]);
            if (!h) out[xfo] = tot + sring[0][0][64 + j];  // + gx entry 2048
        } else if (role == 2) {
            float tot = dot(&sbuf[1][0]);
            ybat[15] = tot + sring[0][0][128 + j];
            if (!h) {
                size_t base = yb + (size_t)(TT - 16) * NYS + j;
                #pragma unroll
                for (int s = 0; s < 16; ++s) out[base + (size_t)s * NYS] = ybat[s];
            }
        }
    } else if (tid < 384) {
        // =================== ring gz wave ===================
        const int j = tid - 320;
        v2f zu1[16], zu2[16];
        #pragma unroll
        for (int t = 0; t < 16; ++t) {
            zu1[t] = (v2f){ Wzt[(64  + 2 * t) * 64 + j], Wzt[(65  + 2 * t) * 64 + j] };
            zu2[t] = (v2f){ Wzt[(160 + 2 * t) * 64 + j], Wzt[(161 + 2 * t) * 64 + j] };
        }
        // prologue: entries 0..15 (entry 0: u_{-1}=0 -> zu2 term only)
        for (int e = 0; e < 16; ++e) {
            v2f a = {0.f, 0.f};
            const float4* C4 = (const float4*)uR[e];
            #pragma unroll
            for (int qq = 0; qq < 8; ++qq) {
                float4 uc = C4[qq];
                a += (v2f){uc.x, uc.y} * zu2[2 * qq] + (v2f){uc.z, uc.w} * zu2[2 * qq + 1];
            }
            if (e > 0) {
                const float4* P4 = (const float4*)uR[e - 1];
                #pragma unroll
                for (int qq = 0; qq < 8; ++qq) {
                    float4 up = P4[qq];
                    a += (v2f){up.x, up.y} * zu1[2 * qq] + (v2f){up.z, up.w} * zu1[2 * qq + 1];
                }
            }
            sring[0][e][j] = a.x + a.y;
        }
        __syncthreads();

        #pragma unroll 2
        for (int i = 0; i < TT; ++i) {
            const int e = i + 16;
            const float4* P4 = (const float4*)uR[(e - 1) & 31];
            const float4* C4 = (const float4*)uR[e & 31];
            v2f a = {0.f, 0.f};
            #pragma unroll
            for (int qq = 0; qq < 8; ++qq) {
                float4 up = P4[qq], uc = C4[qq];
                a += (v2f){up.x, up.y} * zu1[2 * qq] + (v2f){up.z, up.w} * zu1[2 * qq + 1];
                a += (v2f){uc.x, uc.y} * zu2[2 * qq] + (v2f){uc.z, uc.w} * zu2[2 * qq + 1];
            }
            sring[(e >> 4) & 1][e & 15][j] = a.x + a.y;
            step_barrier();
        }
    } else if (tid < 448) {
        // =================== ring gx wave ===================
        const int j = tid - 384;
        v2f xu[16];
        #pragma unroll
        for (int t = 0; t < 16; ++t)
            xu[t] = (v2f){ Wxt[(64 + 2 * t) * 64 + j], Wxt[(65 + 2 * t) * 64 + j] };

        for (int e = 0; e < 16; ++e) {
            v2f a = {0.f, 0.f};
            if (e > 0) {
                const float4* P4 = (const float4*)uR[e - 1];
                #pragma unroll
                for (int qq = 0; qq < 8; ++qq) {
                    float4 up = P4[qq];
                    a += (v2f){up.x, up.y} * xu[2 * qq] + (v2f){up.z, up.w} * xu[2 * qq + 1];
                }
            }
            sring[0][e][64 + j] = a.x + a.y;
        }
        __syncthreads();

        #pragma unroll 2
        for (int i = 0; i < TT; ++i) {
            const int e = i + 16;
            const float4* P4 = (const float4*)uR[(e - 1) & 31];
            v2f a = {0.f, 0.f};
            #pragma unroll
            for (int qq = 0; qq < 8; ++qq) {
                float4 up = P4[qq];
                a += (v2f){up.x, up.y} * xu[2 * qq] + (v2f){up.z, up.w} * xu[2 * qq + 1];
            }
            sring[(e >> 4) & 1][e & 15][64 + j] = a.x + a.y;
            step_barrier();
        }
    } else {
        // =================== ring gy + u-prefetch wave ===================
        const int l = tid - 448;
        const int j = l & 31;
        v2f yu[16];
        #pragma unroll
        for (int t = 0; t < 16; ++t)
            yu[t] = (v2f){ Wyt[(64 + 2 * t) * 32 + j], Wyt[(65 + 2 * t) * 32 + j] };

        for (int e = 0; e < 16; ++e) {
            v2f a = {0.f, 0.f};
            if (e > 0) {
                const float4* P4 = (const float4*)uR[e - 1];
                #pragma unroll
                for (int qq = 0; qq < 8; ++qq) {
                    float4 up = P4[qq];
                    a += (v2f){up.x, up.y} * yu[2 * qq] + (v2f){up.z, up.w} * yu[2 * qq + 1];
                }
            }
            if (l < 32) sring[0][e][128 + j] = a.x + a.y;
        }
        __syncthreads();

        float4 f0, f1;
        const int tq = (l & 3) * 2;
        #pragma unroll 2
        for (int i = 0; i < TT; ++i) {
            if ((i & 15) == 0 && i + 32 < TT) {            // issue loads u_{i+32..i+47}
                int t = i + 32 + (l >> 2);
                f0 = xp4[t * 8 + tq];
                f1 = xp4[t * 8 + tq + 1];
            }
            if ((i & 15) == 8 && i + 24 < TT) {            // land them
                int t = i + 24 + (l >> 2);
                *(float4*)&uR[t & 31][tq * 4]     = f0;
                *(float4*)&uR[t & 31][tq * 4 + 4] = f1;
            }
            const int e = i + 16;
            const float4* P4 = (const float4*)uR[(e - 1) & 31];
            v2f a = {0.f, 0.f};
            #pragma unroll
            for (int qq = 0; qq < 8; ++qq) {
                float4 up = P4[qq];
                a += (v2f){up.x, up.y} * yu[2 * qq] + (v2f){up.z, up.w} * yu[2 * qq + 1];
            }
            if (l < 32) sring[(e >> 4) & 1][e & 15][128 + j] = a.x + a.y;
            step_barrier();
        }
    }
}

// ---------------------------------------------------------------------------
extern "C" void kernel_launch(void* const* d_in, const int* in_sizes, int n_in,
                              void* d_out, int out_size, void* d_ws, size_t ws_size,
                              hipStream_t stream) {
    const float* xp  = (const float*)d_in[0];
    const float* Y   = (const float*)d_in[1];
    const float* lam = (const float*)d_in[2];
    const float* A   = (const float*)d_in[3];
    const float* B1  = (const float*)d_in[4];
    const float* B2  = (const float*)d_in[5];
    const float* C1  = (const float*)d_in[6];
    const float* D11 = (const float*)d_in[7];
    const float* D12 = (const float*)d_in[8];
    const float* C2  = (const float*)d_in[9];
    const float* D21 = (const float*)d_in[10];
    float* out = (float*)d_out;
    float* ws  = (float*)d_ws;

    hipLaunchKernelGGL(setup_inv_kernel,  dim3(1),  dim3(1024), 0, stream, Y, ws);
    hipLaunchKernelGGL(setup_fold_kernel, dim3(16), dim3(256),  0, stream,
                       lam, A, B1, B2, C1, D11, D12, D21, ws);
    hipLaunchKernelGGL(setup_wz_kernel,   dim3(16), dim3(256),  0, stream, lam, C2, ws);
    hipLaunchKernelGGL(rnn4_kernel, dim3(BBATCH), dim3(512), 0, stream, xp, ws, out);
}